// Round 1
// baseline (331.700 us; speedup 1.0000x reference)
//
#include <hip/hip_runtime.h>

#define Tn 512
#define Nn 1024
#define Hn 1024
#define Vn 96103
#define NHEADS 16

// ---- head-average of cross-attn: ca[t,n] = sum_h attn[h,t,n] / 16 ----
__global__ __launch_bounds__(256) void k_headsum(const float* __restrict__ attn,
                                                 float* __restrict__ ca) {
  int i = blockIdx.x * 256 + threadIdx.x;           // float4 index over T*N/4
  const float4* a4 = (const float4*)attn;
  const int slice = (Tn * Nn) / 4;
  float4 acc = a4[i];
#pragma unroll
  for (int h = 1; h < NHEADS; ++h) {
    float4 v = a4[h * slice + i];
    acc.x += v.x; acc.y += v.y; acc.z += v.z; acc.w += v.w;
  }
  const float sc = 1.0f / 16.0f;
  ((float4*)ca)[i] = make_float4(acc.x * sc, acc.y * sc, acc.z * sc, acc.w * sc);
}

// ---- ew[n] = enc[n,:] . w[0:H]  (kills the T x N x H GEMM) ----
__global__ __launch_bounds__(256) void k_ew(const float* __restrict__ enc,
                                            const float* __restrict__ w,
                                            float* __restrict__ ew) {
  int n = blockIdx.x, tid = threadIdx.x;            // H/4 == 256 float4s per row
  float4 r = ((const float4*)(enc + n * Hn))[tid];
  float4 ww = ((const float4*)w)[tid];
  float p = r.x * ww.x + r.y * ww.y + r.z * ww.z + r.w * ww.w;
  for (int off = 32; off > 0; off >>= 1) p += __shfl_down(p, off, 64);
  __shared__ float lds[4];
  int lane = tid & 63, wv = tid >> 6;
  if (lane == 0) lds[wv] = p;
  __syncthreads();
  if (tid == 0) ew[n] = lds[0] + lds[1] + lds[2] + lds[3];
}

// ---- gen_probs[t] = sigmoid(ca[t].ew + dec_h[t].w1 + dec_e[t].w2 + b) ----
__global__ __launch_bounds__(256) void k_gen(const float* __restrict__ ca,
                                             const float* __restrict__ ew,
                                             const float* __restrict__ dh,
                                             const float* __restrict__ de,
                                             const float* __restrict__ w,
                                             const float* __restrict__ b,
                                             float* __restrict__ gen,
                                             float* __restrict__ out_gen) {
  int t = blockIdx.x, tid = threadIdx.x;
  float4 c4 = ((const float4*)(ca + t * Nn))[tid];
  float4 e4 = ((const float4*)ew)[tid];
  float p = c4.x * e4.x + c4.y * e4.y + c4.z * e4.z + c4.w * e4.w;
  float4 h4 = ((const float4*)(dh + t * Hn))[tid];
  float4 w1 = ((const float4*)(w + Hn))[tid];
  p += h4.x * w1.x + h4.y * w1.y + h4.z * w1.z + h4.w * w1.w;
  float4 d4 = ((const float4*)(de + t * Hn))[tid];
  float4 w2 = ((const float4*)(w + 2 * Hn))[tid];
  p += d4.x * w2.x + d4.y * w2.y + d4.z * w2.z + d4.w * w2.w;
  for (int off = 32; off > 0; off >>= 1) p += __shfl_down(p, off, 64);
  __shared__ float lds[4];
  int lane = tid & 63, wv = tid >> 6;
  if (lane == 0) lds[wv] = p;
  __syncthreads();
  if (tid == 0) {
    float z = lds[0] + lds[1] + lds[2] + lds[3] + b[0];
    float g = 1.0f / (1.0f + __expf(-z));
    gen[t] = g;
    out_gen[t] = g;
  }
}

// ---- online softmax stats per row: rowmax[t], rowinv[t] = 1/sum(exp) ----
__global__ __launch_bounds__(256) void k_stats(const float* __restrict__ lg,
                                               float* __restrict__ rowmax,
                                               float* __restrict__ rowinv) {
  int t = blockIdx.x;
  const float* row = lg + (size_t)t * Vn;
  float m = -INFINITY, s = 0.0f;
  for (int v = threadIdx.x; v < Vn; v += 256) {
    float x = row[v];
    if (x > m) { s *= __expf(m - x); m = x; }
    s += __expf(x - m);
  }
  for (int off = 32; off > 0; off >>= 1) {
    float mo = __shfl_down(m, off, 64);
    float so = __shfl_down(s, off, 64);
    float M = fmaxf(m, mo);
    s = s * __expf(m - M) + so * __expf(mo - M);
    m = M;
  }
  __shared__ float lm[4], ls[4];
  int lane = threadIdx.x & 63, wv = threadIdx.x >> 6;
  if (lane == 0) { lm[wv] = m; ls[wv] = s; }
  __syncthreads();
  if (threadIdx.x == 0) {
    float M = fmaxf(fmaxf(lm[0], lm[1]), fmaxf(lm[2], lm[3]));
    float S = ls[0] * __expf(lm[0] - M) + ls[1] * __expf(lm[1] - M) +
              ls[2] * __expf(lm[2] - M) + ls[3] * __expf(lm[3] - M);
    rowmax[t] = M;
    rowinv[t] = 1.0f / S;
  }
}

// ---- dense inverse map of the scatter: col2n[v] = max n with ids[n]==v ----
__global__ __launch_bounds__(256) void k_colinit(int* __restrict__ col2n) {
  int i = blockIdx.x * 256 + threadIdx.x;
  if (i < Vn) col2n[i] = -1;
}
__global__ __launch_bounds__(256) void k_colscatter(const int* __restrict__ ids,
                                                    int* __restrict__ col2n) {
  int n = blockIdx.x * 256 + threadIdx.x;
  if (n < Nn) atomicMax(&col2n[ids[n]], n);   // numpy last-write-wins == max n
}

// ---- fused: out[t,v] = g*softmax(lg)[t,v] + (1-g)*copy_logits[t,v] ----
__global__ __launch_bounds__(256) void k_final(const float* __restrict__ lg,
                                               const float* __restrict__ ca,
                                               const float* __restrict__ gen,
                                               const float* __restrict__ rowmax,
                                               const float* __restrict__ rowinv,
                                               const int* __restrict__ col2n,
                                               float* __restrict__ out) {
  int v = blockIdx.x * 256 + threadIdx.x;
  int t = blockIdx.y;
  if (v >= Vn) return;
  float g = gen[t], m = rowmax[t], inv = rowinv[t];
  size_t idx = (size_t)t * Vn + v;
  float x = lg[idx];
  float val = g * __expf(x - m) * inv;
  int n = col2n[v];
  if (n >= 0) val += (1.0f - g) * ca[t * Nn + n];
  out[idx] = val;
}

extern "C" void kernel_launch(void* const* d_in, const int* in_sizes, int n_in,
                              void* d_out, int out_size, void* d_ws, size_t ws_size,
                              hipStream_t stream) {
  const float* attn = (const float*)d_in[0];
  const float* enc  = (const float*)d_in[1];
  const float* dh   = (const float*)d_in[2];
  const float* de   = (const float*)d_in[3];
  const float* lg   = (const float*)d_in[4];
  const int*   ids  = (const int*)d_in[5];
  const float* w    = (const float*)d_in[6];
  const float* b    = (const float*)d_in[7];
  float* out = (float*)d_out;

  // workspace layout (~2.5 MB)
  float* ca     = (float*)d_ws;          // T*N
  float* ew     = ca + Tn * Nn;          // N
  float* gen    = ew + Nn;               // T
  float* rowmax = gen + Tn;              // T
  float* rowinv = rowmax + Tn;           // T
  int*   col2n  = (int*)(rowinv + Tn);   // V

  hipLaunchKernelGGL(k_headsum, dim3((Tn * Nn / 4) / 256), dim3(256), 0, stream, attn, ca);
  hipLaunchKernelGGL(k_ew, dim3(Nn), dim3(256), 0, stream, enc, w, ew);
  hipLaunchKernelGGL(k_gen, dim3(Tn), dim3(256), 0, stream, ca, ew, dh, de, w, b, gen, out);
  hipLaunchKernelGGL(k_colinit, dim3((Vn + 255) / 256), dim3(256), 0, stream, col2n);
  hipLaunchKernelGGL(k_colscatter, dim3((Nn + 255) / 256), dim3(256), 0, stream, ids, col2n);
  hipLaunchKernelGGL(k_stats, dim3(Tn), dim3(256), 0, stream, lg, rowmax, rowinv);
  hipLaunchKernelGGL(k_final, dim3((Vn + 255) / 256, Tn), dim3(256), 0, stream,
                     lg, ca, gen, rowmax, rowinv, col2n, out + Tn);
}

// Round 2
// 149.571 us; speedup vs baseline: 2.2177x; 2.2177x over previous
//
#include <hip/hip_runtime.h>

#define Tn 512
#define Nn 1024
#define Hn 1024
#define Vn 96103
#define NHEADS 16
#define SPLITS 16
#define CHUNK 6007   // ceil(96103/16)

// ---- head-average of cross-attn: ca[t,n] = sum_h attn[h,t,n] / 16 ----
__global__ __launch_bounds__(256) void k_headsum(const float* __restrict__ attn,
                                                 float* __restrict__ ca) {
  int i = blockIdx.x * 256 + threadIdx.x;           // float4 index over T*N/4
  const float4* a4 = (const float4*)attn;
  const int slice = (Tn * Nn) / 4;
  float4 acc = a4[i];
#pragma unroll
  for (int h = 1; h < NHEADS; ++h) {
    float4 v = a4[h * slice + i];
    acc.x += v.x; acc.y += v.y; acc.z += v.z; acc.w += v.w;
  }
  const float sc = 1.0f / 16.0f;
  ((float4*)ca)[i] = make_float4(acc.x * sc, acc.y * sc, acc.z * sc, acc.w * sc);
}

// ---- ew[n] = enc[n,:] . w[0:H] ----
__global__ __launch_bounds__(256) void k_ew(const float* __restrict__ enc,
                                            const float* __restrict__ w,
                                            float* __restrict__ ew) {
  int n = blockIdx.x, tid = threadIdx.x;
  float4 r = ((const float4*)(enc + n * Hn))[tid];
  float4 ww = ((const float4*)w)[tid];
  float p = r.x * ww.x + r.y * ww.y + r.z * ww.z + r.w * ww.w;
  for (int off = 32; off > 0; off >>= 1) p += __shfl_down(p, off, 64);
  __shared__ float lds[4];
  int lane = tid & 63, wv = tid >> 6;
  if (lane == 0) lds[wv] = p;
  __syncthreads();
  if (tid == 0) ew[n] = lds[0] + lds[1] + lds[2] + lds[3];
}

// ---- gen[t] = sigmoid(ca[t].ew + dec_h[t].w1 + dec_e[t].w2 + b) ----
__global__ __launch_bounds__(256) void k_gen(const float* __restrict__ ca,
                                             const float* __restrict__ ew,
                                             const float* __restrict__ dh,
                                             const float* __restrict__ de,
                                             const float* __restrict__ w,
                                             const float* __restrict__ b,
                                             float* __restrict__ gen,
                                             float* __restrict__ out_gen) {
  int t = blockIdx.x, tid = threadIdx.x;
  float4 c4 = ((const float4*)(ca + t * Nn))[tid];
  float4 e4 = ((const float4*)ew)[tid];
  float p = c4.x * e4.x + c4.y * e4.y + c4.z * e4.z + c4.w * e4.w;
  float4 h4 = ((const float4*)(dh + t * Hn))[tid];
  float4 w1 = ((const float4*)(w + Hn))[tid];
  p += h4.x * w1.x + h4.y * w1.y + h4.z * w1.z + h4.w * w1.w;
  float4 d4 = ((const float4*)(de + t * Hn))[tid];
  float4 w2 = ((const float4*)(w + 2 * Hn))[tid];
  p += d4.x * w2.x + d4.y * w2.y + d4.z * w2.z + d4.w * w2.w;
  for (int off = 32; off > 0; off >>= 1) p += __shfl_down(p, off, 64);
  __shared__ float lds[4];
  int lane = tid & 63, wv = tid >> 6;
  if (lane == 0) lds[wv] = p;
  __syncthreads();
  if (tid == 0) {
    float z = lds[0] + lds[1] + lds[2] + lds[3] + b[0];
    float g = 1.0f / (1.0f + __expf(-z));
    gen[t] = g;
    out_gen[t] = g;
  }
}

// ---- partial online-softmax stats: chunk c of row t -> (m, s) ----
__global__ __launch_bounds__(256) void k_statpart(const float* __restrict__ lg,
                                                  float* __restrict__ part_m,
                                                  float* __restrict__ part_s) {
  const int c = blockIdx.x, t = blockIdx.y;
  const int tid = threadIdx.x;
  const unsigned vbeg = c * CHUNK;
  const unsigned vend = min(vbeg + CHUNK, (unsigned)Vn);
  const unsigned beg = (unsigned)t * Vn + vbeg;
  const unsigned end = (unsigned)t * Vn + vend;
  const unsigned beg4 = (beg + 3u) & ~3u;   // first 16B-aligned element
  const unsigned end4 = end & ~3u;          // end of aligned region

  float m = -INFINITY, s = 0.0f;
  // head scalars (<=3)
  for (unsigned i = beg + tid; i < beg4; i += 256) {
    float x = lg[i];
    if (x > m) { s *= __expf(m - x); m = x; }
    s += __expf(x - m);
  }
  // aligned float4 body
  const float4* lg4 = (const float4*)lg;
  for (unsigned i4 = beg4 / 4 + tid; i4 < end4 / 4; i4 += 256) {
    float4 a = lg4[i4];
    float mx = fmaxf(fmaxf(a.x, a.y), fmaxf(a.z, a.w));
    if (mx > m) { s *= __expf(m - mx); m = mx; }
    s += __expf(a.x - m) + __expf(a.y - m) + __expf(a.z - m) + __expf(a.w - m);
  }
  // tail scalars (<=3)
  for (unsigned i = end4 + tid; i < end; i += 256) {
    float x = lg[i];
    if (x > m) { s *= __expf(m - x); m = x; }
    s += __expf(x - m);
  }
  // block reduce (m,s)
  for (int off = 32; off > 0; off >>= 1) {
    float mo = __shfl_down(m, off, 64);
    float so = __shfl_down(s, off, 64);
    float M = fmaxf(m, mo);
    s = s * __expf(m - M) + so * __expf(mo - M);
    m = M;
  }
  __shared__ float lm[4], ls[4];
  int lane = tid & 63, wv = tid >> 6;
  if (lane == 0) { lm[wv] = m; ls[wv] = s; }
  __syncthreads();
  if (tid == 0) {
    float M = fmaxf(fmaxf(lm[0], lm[1]), fmaxf(lm[2], lm[3]));
    float S = ls[0] * __expf(lm[0] - M) + ls[1] * __expf(lm[1] - M) +
              ls[2] * __expf(lm[2] - M) + ls[3] * __expf(lm[3] - M);
    part_m[t * SPLITS + c] = M;
    part_s[t * SPLITS + c] = S;
  }
}

// ---- combine partials + pack per-row params (g, rowmax, rowinv, 1-g) ----
__global__ __launch_bounds__(256) void k_statcombine(const float* __restrict__ part_m,
                                                     const float* __restrict__ part_s,
                                                     const float* __restrict__ gen,
                                                     float4* __restrict__ params) {
  int t = blockIdx.x * 256 + threadIdx.x;
  if (t >= Tn) return;
  float M = -INFINITY, S = 0.0f;
#pragma unroll
  for (int c = 0; c < SPLITS; ++c) {
    float mp = part_m[t * SPLITS + c];
    float sp = part_s[t * SPLITS + c];
    float Mn = fmaxf(M, mp);
    S = S * __expf(M - Mn) + sp * __expf(mp - Mn);
    M = Mn;
  }
  float g = gen[t];
  params[t] = make_float4(g, M, 1.0f / S, 1.0f - g);
}

// ---- dense inverse map of the scatter ----
__global__ __launch_bounds__(256) void k_colinit(int* __restrict__ col2n) {
  int i = blockIdx.x * 256 + threadIdx.x;
  if (i < Vn) col2n[i] = -1;
}
__global__ __launch_bounds__(256) void k_colscatter(const int* __restrict__ ids,
                                                    int* __restrict__ col2n) {
  int n = blockIdx.x * 256 + threadIdx.x;
  if (n < Nn) atomicMax(&col2n[ids[n]], n);   // numpy last-write-wins == max n
}

// ---- fused final: out[t,v] = g*softmax + (1-g)*copy, flat float4 ----
__global__ __launch_bounds__(256) void k_final(const float* __restrict__ lg,
                                               const float* __restrict__ ca,
                                               const float4* __restrict__ params,
                                               const int* __restrict__ col2n,
                                               float* __restrict__ out) {
  const unsigned total4 = ((unsigned)Tn * (unsigned)Vn) / 4u;   // 12301184
  const float4* lg4 = (const float4*)lg;
  float4* out4 = (float4*)out;
  for (unsigned i4 = blockIdx.x * 256u + threadIdx.x; i4 < total4;
       i4 += gridDim.x * 256u) {
    unsigned i0 = i4 * 4u;
    unsigned t = i0 / (unsigned)Vn;
    unsigned v = i0 - t * (unsigned)Vn;
    float4 x = lg4[i4];
    float4 r;
    if (v + 3u < (unsigned)Vn) {                // whole quad in one row
      float4 P = params[t];
      int n0 = col2n[v], n1 = col2n[v + 1], n2 = col2n[v + 2], n3 = col2n[v + 3];
      r.x = P.x * __expf(x.x - P.y) * P.z;
      r.y = P.x * __expf(x.y - P.y) * P.z;
      r.z = P.x * __expf(x.z - P.y) * P.z;
      r.w = P.x * __expf(x.w - P.y) * P.z;
      const float* cat = ca + t * Nn;
      if (n0 >= 0) r.x += P.w * cat[n0];
      if (n1 >= 0) r.y += P.w * cat[n1];
      if (n2 >= 0) r.z += P.w * cat[n2];
      if (n3 >= 0) r.w += P.w * cat[n3];
    } else {                                    // row-spanning quad (rare)
      float* rp = &r.x;
      const float* xp = &x.x;
#pragma unroll
      for (int j = 0; j < 4; ++j) {
        unsigned idx = i0 + j;
        unsigned tt = idx / (unsigned)Vn;
        unsigned vv = idx - tt * (unsigned)Vn;
        float4 P = params[tt];
        int n = col2n[vv];
        float val = P.x * __expf(xp[j] - P.y) * P.z;
        if (n >= 0) val += P.w * ca[tt * Nn + n];
        rp[j] = val;
      }
    }
    out4[i4] = r;
  }
}

extern "C" void kernel_launch(void* const* d_in, const int* in_sizes, int n_in,
                              void* d_out, int out_size, void* d_ws, size_t ws_size,
                              hipStream_t stream) {
  const float* attn = (const float*)d_in[0];
  const float* enc  = (const float*)d_in[1];
  const float* dh   = (const float*)d_in[2];
  const float* de   = (const float*)d_in[3];
  const float* lg   = (const float*)d_in[4];
  const int*   ids  = (const int*)d_in[5];
  const float* w    = (const float*)d_in[6];
  const float* b    = (const float*)d_in[7];
  float* out = (float*)d_out;

  // workspace layout (params first for 16B alignment)
  float4* params = (float4*)d_ws;                 // T float4s
  float* ca     = (float*)(params + Tn);          // T*N
  float* ew     = ca + Tn * Nn;                   // N
  float* gen    = ew + Nn;                        // T
  float* part_m = gen + Tn;                       // T*SPLITS
  float* part_s = part_m + Tn * SPLITS;           // T*SPLITS
  int*   col2n  = (int*)(part_s + Tn * SPLITS);   // V

  hipLaunchKernelGGL(k_headsum, dim3((Tn * Nn / 4) / 256), dim3(256), 0, stream, attn, ca);
  hipLaunchKernelGGL(k_ew, dim3(Nn), dim3(256), 0, stream, enc, w, ew);
  hipLaunchKernelGGL(k_gen, dim3(Tn), dim3(256), 0, stream, ca, ew, dh, de, w, b, gen, out);
  hipLaunchKernelGGL(k_colinit, dim3((Vn + 255) / 256), dim3(256), 0, stream, col2n);
  hipLaunchKernelGGL(k_colscatter, dim3((Nn + 255) / 256), dim3(256), 0, stream, ids, col2n);
  hipLaunchKernelGGL(k_statpart, dim3(SPLITS, Tn), dim3(256), 0, stream, lg, part_m, part_s);
  hipLaunchKernelGGL(k_statcombine, dim3((Tn + 255) / 256), dim3(256), 0, stream,
                     part_m, part_s, gen, params);
  hipLaunchKernelGGL(k_final, dim3(4096), dim3(256), 0, stream,
                     lg, ca, params, col2n, out + Tn);
}

// Round 4
// 124.829 us; speedup vs baseline: 2.6572x; 1.1982x over previous
//
#include <hip/hip_runtime.h>

#define Tn 512
#define Nn 1024
#define Hn 1024
#define Vn 96103
#define NHEADS 16
#define SPLITS 16
#define CHUNK 6007   // ceil(96103/16)

typedef float f4 __attribute__((ext_vector_type(4)));   // nontemporal-compatible

// ---- head-average of cross-attn + col2n init (piggybacked) ----
__global__ __launch_bounds__(256) void k_headsum(const float* __restrict__ attn,
                                                 float* __restrict__ ca,
                                                 int* __restrict__ col2n) {
  int i = blockIdx.x * 256 + threadIdx.x;           // float4 index over T*N/4
  if (i < Vn) col2n[i] = -1;                        // piggyback init
  const f4* a4 = (const f4*)attn;
  const int slice = (Tn * Nn) / 4;
  f4 acc = __builtin_nontemporal_load(&a4[i]);
#pragma unroll
  for (int h = 1; h < NHEADS; ++h) {
    f4 v = __builtin_nontemporal_load(&a4[h * slice + i]);
    acc += v;
  }
  ((f4*)ca)[i] = acc * (1.0f / 16.0f);
}

// ---- ew[n] = enc[n,:] . w[0:H]  + colscatter (piggybacked) ----
__global__ __launch_bounds__(256) void k_ew(const float* __restrict__ enc,
                                            const float* __restrict__ w,
                                            float* __restrict__ ew,
                                            const int* __restrict__ ids,
                                            int* __restrict__ col2n) {
  int n = blockIdx.x, tid = threadIdx.x;
  if (tid == 0) atomicMax(&col2n[ids[n]], n);   // numpy last-write-wins == max n
  float4 r = ((const float4*)(enc + n * Hn))[tid];
  float4 ww = ((const float4*)w)[tid];
  float p = r.x * ww.x + r.y * ww.y + r.z * ww.z + r.w * ww.w;
  for (int off = 32; off > 0; off >>= 1) p += __shfl_down(p, off, 64);
  __shared__ float lds[4];
  int lane = tid & 63, wv = tid >> 6;
  if (lane == 0) lds[wv] = p;
  __syncthreads();
  if (tid == 0) ew[n] = lds[0] + lds[1] + lds[2] + lds[3];
}

// ---- gen[t] = sigmoid(ca[t].ew + dec_h[t].w1 + dec_e[t].w2 + b) ----
__global__ __launch_bounds__(256) void k_gen(const float* __restrict__ ca,
                                             const float* __restrict__ ew,
                                             const float* __restrict__ dh,
                                             const float* __restrict__ de,
                                             const float* __restrict__ w,
                                             const float* __restrict__ b,
                                             float* __restrict__ gen,
                                             float* __restrict__ out_gen) {
  int t = blockIdx.x, tid = threadIdx.x;
  float4 c4 = ((const float4*)(ca + t * Nn))[tid];
  float4 e4 = ((const float4*)ew)[tid];
  float p = c4.x * e4.x + c4.y * e4.y + c4.z * e4.z + c4.w * e4.w;
  float4 h4 = ((const float4*)(dh + t * Hn))[tid];
  float4 w1 = ((const float4*)(w + Hn))[tid];
  p += h4.x * w1.x + h4.y * w1.y + h4.z * w1.z + h4.w * w1.w;
  float4 d4 = ((const float4*)(de + t * Hn))[tid];
  float4 w2 = ((const float4*)(w + 2 * Hn))[tid];
  p += d4.x * w2.x + d4.y * w2.y + d4.z * w2.z + d4.w * w2.w;
  for (int off = 32; off > 0; off >>= 1) p += __shfl_down(p, off, 64);
  __shared__ float lds[4];
  int lane = tid & 63, wv = tid >> 6;
  if (lane == 0) lds[wv] = p;
  __syncthreads();
  if (tid == 0) {
    float z = lds[0] + lds[1] + lds[2] + lds[3] + b[0];
    float g = 1.0f / (1.0f + __expf(-z));
    gen[t] = g;
    out_gen[t] = g;
  }
}

// ---- partial online-softmax stats: chunk c of row t -> (m, s) ----
__global__ __launch_bounds__(256) void k_statpart(const float* __restrict__ lg,
                                                  float* __restrict__ part_m,
                                                  float* __restrict__ part_s) {
  const int c = blockIdx.x, t = blockIdx.y;
  const int tid = threadIdx.x;
  const unsigned vbeg = c * CHUNK;
  const unsigned vend = min(vbeg + CHUNK, (unsigned)Vn);
  const unsigned beg = (unsigned)t * Vn + vbeg;
  const unsigned end = (unsigned)t * Vn + vend;
  const unsigned beg4 = (beg + 3u) & ~3u;
  const unsigned end4 = end & ~3u;

  float m = -INFINITY, s = 0.0f;
  for (unsigned i = beg + tid; i < beg4; i += 256) {
    float x = lg[i];
    if (x > m) { s *= __expf(m - x); m = x; }
    s += __expf(x - m);
  }
  const float4* lg4 = (const float4*)lg;
  for (unsigned i4 = beg4 / 4 + tid; i4 < end4 / 4; i4 += 256) {
    float4 a = lg4[i4];
    float mx = fmaxf(fmaxf(a.x, a.y), fmaxf(a.z, a.w));
    if (mx > m) { s *= __expf(m - mx); m = mx; }
    s += __expf(a.x - m) + __expf(a.y - m) + __expf(a.z - m) + __expf(a.w - m);
  }
  for (unsigned i = end4 + tid; i < end; i += 256) {
    float x = lg[i];
    if (x > m) { s *= __expf(m - x); m = x; }
    s += __expf(x - m);
  }
  for (int off = 32; off > 0; off >>= 1) {
    float mo = __shfl_down(m, off, 64);
    float so = __shfl_down(s, off, 64);
    float M = fmaxf(m, mo);
    s = s * __expf(m - M) + so * __expf(mo - M);
    m = M;
  }
  __shared__ float lm[4], ls[4];
  int lane = tid & 63, wv = tid >> 6;
  if (lane == 0) { lm[wv] = m; ls[wv] = s; }
  __syncthreads();
  if (tid == 0) {
    float M = fmaxf(fmaxf(lm[0], lm[1]), fmaxf(lm[2], lm[3]));
    float S = ls[0] * __expf(lm[0] - M) + ls[1] * __expf(lm[1] - M) +
              ls[2] * __expf(lm[2] - M) + ls[3] * __expf(lm[3] - M);
    part_m[t * SPLITS + c] = M;
    part_s[t * SPLITS + c] = S;
  }
}

// ---- combine partials + pack per-row params (g, rowmax, rowinv, 1-g) ----
__global__ __launch_bounds__(256) void k_statcombine(const float* __restrict__ part_m,
                                                     const float* __restrict__ part_s,
                                                     const float* __restrict__ gen,
                                                     float4* __restrict__ params) {
  int t = blockIdx.x * 256 + threadIdx.x;
  if (t >= Tn) return;
  float M = -INFINITY, S = 0.0f;
#pragma unroll
  for (int c = 0; c < SPLITS; ++c) {
    float mp = part_m[t * SPLITS + c];
    float sp = part_s[t * SPLITS + c];
    float Mn = fmaxf(M, mp);
    S = S * __expf(M - Mn) + sp * __expf(mp - Mn);
    M = Mn;
  }
  float g = gen[t];
  params[t] = make_float4(g, M, 1.0f / S, 1.0f - g);
}

// ---- fused final: out[t,v] = g*softmax + (1-g)*copy, flat float4, nt I/O ----
__global__ __launch_bounds__(256) void k_final(const float* __restrict__ lg,
                                               const float* __restrict__ ca,
                                               const float4* __restrict__ params,
                                               const int* __restrict__ col2n,
                                               float* __restrict__ out) {
  const unsigned total4 = ((unsigned)Tn * (unsigned)Vn) / 4u;   // 12301184
  const f4* lg4 = (const f4*)lg;
  f4* out4 = (f4*)out;
  for (unsigned i4 = blockIdx.x * 256u + threadIdx.x; i4 < total4;
       i4 += gridDim.x * 256u) {
    unsigned i0 = i4 * 4u;
    unsigned t = i0 / (unsigned)Vn;
    unsigned v = i0 - t * (unsigned)Vn;
    f4 x = __builtin_nontemporal_load(&lg4[i4]);
    f4 r;
    if (v + 3u < (unsigned)Vn) {                // whole quad in one row
      float4 P = params[t];
      int n0 = col2n[v], n1 = col2n[v + 1], n2 = col2n[v + 2], n3 = col2n[v + 3];
      r[0] = P.x * __expf(x[0] - P.y) * P.z;
      r[1] = P.x * __expf(x[1] - P.y) * P.z;
      r[2] = P.x * __expf(x[2] - P.y) * P.z;
      r[3] = P.x * __expf(x[3] - P.y) * P.z;
      const float* cat = ca + t * Nn;
      if (n0 >= 0) r[0] += P.w * cat[n0];
      if (n1 >= 0) r[1] += P.w * cat[n1];
      if (n2 >= 0) r[2] += P.w * cat[n2];
      if (n3 >= 0) r[3] += P.w * cat[n3];
    } else {                                    // row-spanning quad (rare)
#pragma unroll
      for (int j = 0; j < 4; ++j) {
        unsigned idx = i0 + j;
        unsigned tt = idx / (unsigned)Vn;
        unsigned vv = idx - tt * (unsigned)Vn;
        float4 P = params[tt];
        int n = col2n[vv];
        float val = P.x * __expf(x[j] - P.y) * P.z;
        if (n >= 0) val += P.w * ca[tt * Nn + n];
        r[j] = val;
      }
    }
    __builtin_nontemporal_store(r, &out4[i4]);
  }
}

extern "C" void kernel_launch(void* const* d_in, const int* in_sizes, int n_in,
                              void* d_out, int out_size, void* d_ws, size_t ws_size,
                              hipStream_t stream) {
  const float* attn = (const float*)d_in[0];
  const float* enc  = (const float*)d_in[1];
  const float* dh   = (const float*)d_in[2];
  const float* de   = (const float*)d_in[3];
  const float* lg   = (const float*)d_in[4];
  const int*   ids  = (const int*)d_in[5];
  const float* w    = (const float*)d_in[6];
  const float* b    = (const float*)d_in[7];
  float* out = (float*)d_out;

  // workspace layout (params first for 16B alignment)
  float4* params = (float4*)d_ws;                 // T float4s
  float* ca     = (float*)(params + Tn);          // T*N
  float* ew     = ca + Tn * Nn;                   // N
  float* gen    = ew + Nn;                        // T
  float* part_m = gen + Tn;                       // T*SPLITS
  float* part_s = part_m + Tn * SPLITS;           // T*SPLITS
  int*   col2n  = (int*)(part_s + Tn * SPLITS);   // V

  hipLaunchKernelGGL(k_headsum, dim3((Tn * Nn / 4) / 256), dim3(256), 0, stream,
                     attn, ca, col2n);
  hipLaunchKernelGGL(k_ew, dim3(Nn), dim3(256), 0, stream, enc, w, ew, ids, col2n);
  hipLaunchKernelGGL(k_gen, dim3(Tn), dim3(256), 0, stream, ca, ew, dh, de, w, b, gen, out);
  hipLaunchKernelGGL(k_statpart, dim3(SPLITS, Tn), dim3(256), 0, stream, lg, part_m, part_s);
  hipLaunchKernelGGL(k_statcombine, dim3((Tn + 255) / 256), dim3(256), 0, stream,
                     part_m, part_s, gen, params);
  hipLaunchKernelGGL(k_final, dim3(4096), dim3(256), 0, stream,
                     lg, ca, params, col2n, out + Tn);
}

// Round 5
// 117.857 us; speedup vs baseline: 2.8144x; 1.0592x over previous
//
#include <hip/hip_runtime.h>

#define Tn 512
#define Nn 1024
#define Hn 1024
#define Vn 96103
#define NHEADS 16
#define SPLITS 16
#define CHUNK 6007   // ceil(96103/16)

#define HS_BLKS 512          // headsum: T*N/4 / 256
#define EW_BLKS 1024         // one per encoder token
#define SP_BLKS (SPLITS*Tn)  // statpart: 8192
#define K0_BLKS (HS_BLKS + EW_BLKS + SP_BLKS)

typedef float f4 __attribute__((ext_vector_type(4)));   // nontemporal-compatible

// ================= K0: headsum+colinit | ew | statpart =================
__global__ __launch_bounds__(256) void k0(const float* __restrict__ attn,
                                          const float* __restrict__ enc,
                                          const float* __restrict__ w,
                                          const float* __restrict__ lg,
                                          float* __restrict__ ca,
                                          float* __restrict__ ew,
                                          float* __restrict__ part_m,
                                          float* __restrict__ part_s,
                                          int* __restrict__ col2n) {
  const int b = blockIdx.x, tid = threadIdx.x;

  if (b < HS_BLKS) {
    // ---- head-average of cross-attn + col2n init ----
    int i = b * 256 + tid;                     // float4 index over T*N/4
    if (i < Vn) col2n[i] = -1;                 // 131072 threads cover Vn
    const f4* a4 = (const f4*)attn;
    const int slice = (Tn * Nn) / 4;
    f4 acc = __builtin_nontemporal_load(&a4[i]);
#pragma unroll
    for (int h = 1; h < NHEADS; ++h)
      acc += __builtin_nontemporal_load(&a4[h * slice + i]);
    ((f4*)ca)[i] = acc * (1.0f / 16.0f);
    return;
  }

  if (b < HS_BLKS + EW_BLKS) {
    // ---- ew[n] = enc[n,:] . w[0:H] ----
    int n = b - HS_BLKS;
    float4 r = ((const float4*)(enc + n * Hn))[tid];
    float4 ww = ((const float4*)w)[tid];
    float p = r.x * ww.x + r.y * ww.y + r.z * ww.z + r.w * ww.w;
    for (int off = 32; off > 0; off >>= 1) p += __shfl_down(p, off, 64);
    __shared__ float lds[4];
    int lane = tid & 63, wv = tid >> 6;
    if (lane == 0) lds[wv] = p;
    __syncthreads();
    if (tid == 0) ew[n] = lds[0] + lds[1] + lds[2] + lds[3];
    return;
  }

  // ---- partial online-softmax stats: chunk c of row t ----
  {
    int rem = b - HS_BLKS - EW_BLKS;
    const int c = rem & (SPLITS - 1), t = rem >> 4;
    const unsigned vbeg = c * CHUNK;
    const unsigned vend = min(vbeg + CHUNK, (unsigned)Vn);
    const unsigned beg = (unsigned)t * Vn + vbeg;
    const unsigned end = (unsigned)t * Vn + vend;
    const unsigned beg4 = (beg + 3u) & ~3u;
    const unsigned end4 = end & ~3u;

    float m = -INFINITY, s = 0.0f;
    for (unsigned i = beg + tid; i < beg4; i += 256) {
      float x = lg[i];
      if (x > m) { s *= __expf(m - x); m = x; }
      s += __expf(x - m);
    }
    const float4* lg4 = (const float4*)lg;
    for (unsigned i4 = beg4 / 4 + tid; i4 < end4 / 4; i4 += 256) {
      float4 a = lg4[i4];
      float mx = fmaxf(fmaxf(a.x, a.y), fmaxf(a.z, a.w));
      if (mx > m) { s *= __expf(m - mx); m = mx; }
      s += __expf(a.x - m) + __expf(a.y - m) + __expf(a.z - m) + __expf(a.w - m);
    }
    for (unsigned i = end4 + tid; i < end; i += 256) {
      float x = lg[i];
      if (x > m) { s *= __expf(m - x); m = x; }
      s += __expf(x - m);
    }
    for (int off = 32; off > 0; off >>= 1) {
      float mo = __shfl_down(m, off, 64);
      float so = __shfl_down(s, off, 64);
      float M = fmaxf(m, mo);
      s = s * __expf(m - M) + so * __expf(mo - M);
      m = M;
    }
    __shared__ float lm[4], ls[4];
    int lane = tid & 63, wv = tid >> 6;
    if (lane == 0) { lm[wv] = m; ls[wv] = s; }
    __syncthreads();
    if (tid == 0) {
      float M = fmaxf(fmaxf(lm[0], lm[1]), fmaxf(lm[2], lm[3]));
      float S = ls[0] * __expf(lm[0] - M) + ls[1] * __expf(lm[1] - M) +
                ls[2] * __expf(lm[2] - M) + ls[3] * __expf(lm[3] - M);
      part_m[t * SPLITS + c] = M;
      part_s[t * SPLITS + c] = S;
    }
  }
}

// ===== K1: per-row gen + stat-combine -> params; block Tn does colscatter =====
__global__ __launch_bounds__(256) void k1(const float* __restrict__ ca,
                                          const float* __restrict__ ew,
                                          const float* __restrict__ dh,
                                          const float* __restrict__ de,
                                          const float* __restrict__ w,
                                          const float* __restrict__ b,
                                          const float* __restrict__ part_m,
                                          const float* __restrict__ part_s,
                                          const int* __restrict__ ids,
                                          int* __restrict__ col2n,
                                          float4* __restrict__ params,
                                          float* __restrict__ out_gen) {
  const int t = blockIdx.x, tid = threadIdx.x;
  if (t == Tn) {               // colscatter (after K0's colinit kernel boundary)
    for (int n = tid; n < Nn; n += 256)
      atomicMax(&col2n[ids[n]], n);            // numpy last-write-wins == max n
    return;
  }
  float4 c4 = ((const float4*)(ca + t * Nn))[tid];
  float4 e4 = ((const float4*)ew)[tid];
  float p = c4.x * e4.x + c4.y * e4.y + c4.z * e4.z + c4.w * e4.w;
  float4 h4 = ((const float4*)(dh + t * Hn))[tid];
  float4 w1 = ((const float4*)(w + Hn))[tid];
  p += h4.x * w1.x + h4.y * w1.y + h4.z * w1.z + h4.w * w1.w;
  float4 d4 = ((const float4*)(de + t * Hn))[tid];
  float4 w2 = ((const float4*)(w + 2 * Hn))[tid];
  p += d4.x * w2.x + d4.y * w2.y + d4.z * w2.z + d4.w * w2.w;
  for (int off = 32; off > 0; off >>= 1) p += __shfl_down(p, off, 64);
  __shared__ float lds[4];
  int lane = tid & 63, wv = tid >> 6;
  if (lane == 0) lds[wv] = p;
  __syncthreads();
  if (tid == 0) {
    float z = lds[0] + lds[1] + lds[2] + lds[3] + b[0];
    float g = 1.0f / (1.0f + __expf(-z));
    float M = -INFINITY, S = 0.0f;
#pragma unroll
    for (int c = 0; c < SPLITS; ++c) {
      float mp = part_m[t * SPLITS + c];
      float sp = part_s[t * SPLITS + c];
      float Mn = fmaxf(M, mp);
      S = S * __expf(M - Mn) + sp * __expf(mp - Mn);
      M = Mn;
    }
    out_gen[t] = g;
    params[t] = make_float4(g, M, 1.0f / S, 1.0f - g);
  }
}

// ===== K2: out[t,v] = g*softmax + (1-g)*copy, flat float4, nt I/O =====
__global__ __launch_bounds__(256) void k2(const float* __restrict__ lg,
                                          const float* __restrict__ ca,
                                          const float4* __restrict__ params,
                                          const int* __restrict__ col2n,
                                          float* __restrict__ out) {
  const unsigned total4 = ((unsigned)Tn * (unsigned)Vn) / 4u;   // 12301184
  const f4* lg4 = (const f4*)lg;
  f4* out4 = (f4*)out;
  for (unsigned i4 = blockIdx.x * 256u + threadIdx.x; i4 < total4;
       i4 += gridDim.x * 256u) {
    unsigned i0 = i4 * 4u;
    unsigned t = i0 / (unsigned)Vn;
    unsigned v = i0 - t * (unsigned)Vn;
    f4 x = __builtin_nontemporal_load(&lg4[i4]);
    f4 r;
    if (v + 3u < (unsigned)Vn) {                // whole quad in one row
      float4 P = params[t];
      int n0 = col2n[v], n1 = col2n[v + 1], n2 = col2n[v + 2], n3 = col2n[v + 3];
      r[0] = P.x * __expf(x[0] - P.y) * P.z;
      r[1] = P.x * __expf(x[1] - P.y) * P.z;
      r[2] = P.x * __expf(x[2] - P.y) * P.z;
      r[3] = P.x * __expf(x[3] - P.y) * P.z;
      const float* cat = ca + t * Nn;
      if (n0 >= 0) r[0] += P.w * cat[n0];
      if (n1 >= 0) r[1] += P.w * cat[n1];
      if (n2 >= 0) r[2] += P.w * cat[n2];
      if (n3 >= 0) r[3] += P.w * cat[n3];
    } else {                                    // row-spanning quad (rare)
#pragma unroll
      for (int j = 0; j < 4; ++j) {
        unsigned idx = i0 + j;
        unsigned tt = idx / (unsigned)Vn;
        unsigned vv = idx - tt * (unsigned)Vn;
        float4 P = params[tt];
        int n = col2n[vv];
        float val = P.x * __expf(x[j] - P.y) * P.z;
        if (n >= 0) val += P.w * ca[tt * Nn + n];
        r[j] = val;
      }
    }
    __builtin_nontemporal_store(r, &out4[i4]);
  }
}

extern "C" void kernel_launch(void* const* d_in, const int* in_sizes, int n_in,
                              void* d_out, int out_size, void* d_ws, size_t ws_size,
                              hipStream_t stream) {
  const float* attn = (const float*)d_in[0];
  const float* enc  = (const float*)d_in[1];
  const float* dh   = (const float*)d_in[2];
  const float* de   = (const float*)d_in[3];
  const float* lg   = (const float*)d_in[4];
  const int*   ids  = (const int*)d_in[5];
  const float* w    = (const float*)d_in[6];
  const float* b    = (const float*)d_in[7];
  float* out = (float*)d_out;

  // workspace layout (params first for 16B alignment)
  float4* params = (float4*)d_ws;                 // T float4s
  float* ca     = (float*)(params + Tn);          // T*N
  float* ew     = ca + Tn * Nn;                   // N
  float* part_m = ew + Nn;                        // T*SPLITS
  float* part_s = part_m + Tn * SPLITS;           // T*SPLITS
  int*   col2n  = (int*)(part_s + Tn * SPLITS);   // V

  hipLaunchKernelGGL(k0, dim3(K0_BLKS), dim3(256), 0, stream,
                     attn, enc, w, lg, ca, ew, part_m, part_s, col2n);
  hipLaunchKernelGGL(k1, dim3(Tn + 1), dim3(256), 0, stream,
                     ca, ew, dh, de, w, b, part_m, part_s, ids, col2n, params, out);
  hipLaunchKernelGGL(k2, dim3(4096), dim3(256), 0, stream,
                     lg, ca, params, col2n, out + Tn);
}